// Round 11
// baseline (582.414 us; speedup 1.0000x reference)
//
#include <hip/hip_runtime.h>
#include <math.h>

#define M_ROWS 2048
#define N_COLS 2048
#define DIMS 512
#define IN_STRIDE 513
#define DP_BLOCKS 32
#define DP_COLS 64
#define BAND 16

constexpr float GAMMA = 0.001f;
constexpr float LOG2E = 1.44269504088896f;
constexpr float LN2   = 0.69314718055995f;

__device__ __forceinline__ float fexp2(float x) { return __builtin_amdgcn_exp2f(x); }
__device__ __forceinline__ float flog2(float x) { return __builtin_amdgcn_logf(x); }

// round-to-nearest-even fp32 -> bf16 (bit trick; values are tame, no NaN/Inf)
__device__ __forceinline__ unsigned short f2bf(float x) {
    unsigned u = __float_as_uint(x);
    return (unsigned short)((u + 0x7FFFu + ((u >> 16) & 1u)) >> 16);
}
__device__ __forceinline__ float bf2f(unsigned short u) {
    return __uint_as_float((unsigned)u << 16);
}

// ---------------- argsort by timestamp (last column), stable ----------------
__global__ void argsort_kernel(const float* __restrict__ a, const float* __restrict__ b,
                               int* __restrict__ permA, int* __restrict__ permB) {
    const float* src = blockIdx.y ? b : a;
    int* perm = blockIdx.y ? permB : permA;
    __shared__ float keys[M_ROWS];
    for (int j = threadIdx.x; j < M_ROWS; j += blockDim.x)
        keys[j] = src[(size_t)j * IN_STRIDE + DIMS];
    __syncthreads();
    int i = blockIdx.x * blockDim.x + threadIdx.x;
    float ki = keys[i];
    int rank = 0;
    for (int j = 0; j < M_ROWS; ++j) {
        float kj = keys[j];
        rank += (kj < ki) || (kj == ki && j < i);
    }
    perm[rank] = i;
}

// ---- gather sorted rows + L2-normalize; emit split-bf16 (hi + residual-lo) ----
__global__ __launch_bounds__(128) void norm_kernel(const float* __restrict__ a, const float* __restrict__ b,
                                                   const int* __restrict__ permA, const int* __restrict__ permB,
                                                   unsigned short* __restrict__ Ahi, unsigned short* __restrict__ Alo,
                                                   unsigned short* __restrict__ Bhi, unsigned short* __restrict__ Blo) {
    const float* src = blockIdx.y ? b : a;
    const int* perm = blockIdx.y ? permB : permA;
    unsigned short* dhi = blockIdx.y ? Bhi : Ahi;
    unsigned short* dlo = blockIdx.y ? Blo : Alo;
    int r = blockIdx.x;
    int row = perm[r];
    const float* p = src + (size_t)row * IN_STRIDE;
    int tid = threadIdx.x;
    float v0 = p[tid], v1 = p[tid + 128], v2 = p[tid + 256], v3 = p[tid + 384];
    float ss = v0 * v0 + v1 * v1 + v2 * v2 + v3 * v3;
    #pragma unroll
    for (int off = 32; off > 0; off >>= 1) ss += __shfl_down(ss, off);
    __shared__ float red[2];
    if ((tid & 63) == 0) red[tid >> 6] = ss;
    __syncthreads();
    float inv = 1.0f / sqrtf(red[0] + red[1] + 1e-10f);
    unsigned short* qh = dhi + (size_t)r * DIMS;
    unsigned short* ql = dlo + (size_t)r * DIMS;
    float x;
    unsigned short h;
    x = v0 * inv; h = f2bf(x); qh[tid]       = h; ql[tid]       = f2bf(x - bf2f(h));
    x = v1 * inv; h = f2bf(x); qh[tid + 128] = h; ql[tid + 128] = f2bf(x - bf2f(h));
    x = v2 * inv; h = f2bf(x); qh[tid + 256] = h; ql[tid + 256] = f2bf(x - bf2f(h));
    x = v3 * inv; h = f2bf(x); qh[tid + 384] = h; ql[tid + 384] = f2bf(x - bf2f(h));
}

// ---------------- GEMM via split-bf16 3-pass MFMA ----------------
// Q[i][n] = exp(-1 - dot(Ahat[i], Bhat[n])); dot via hi*hi + hi*lo + lo*hi
// (lo*lo ~ 2e-7, negligible).  mfma_f32_16x16x32_bf16 fragments:
//   A/B: lane holds 8 consecutive-k bf16 at row=lane&15, k=8*(lane>>4)+j
//   C/D: col=lane&15, row=(lane>>4)*4+reg   [m89-verified]
typedef __attribute__((ext_vector_type(8))) short bf16x8;
typedef __attribute__((ext_vector_type(4))) float f32x4;

__global__ __launch_bounds__(256) void gemm_kernel(const unsigned short* __restrict__ Ahi,
                                                   const unsigned short* __restrict__ Alo,
                                                   const unsigned short* __restrict__ Bhi,
                                                   const unsigned short* __restrict__ Blo,
                                                   float* __restrict__ Q) {
    const int tid = threadIdx.x;
    const int lane = tid & 63;
    const int wv = tid >> 6;                        // 0..3
    const int row0 = blockIdx.y * 64 + (wv >> 1) * 32;
    const int col0 = blockIdx.x * 64 + (wv & 1) * 32;
    const int lr = lane & 15;
    const int kj = (lane >> 4) * 8;
    const size_t ar0 = (size_t)(row0 + lr) * DIMS + kj;
    const size_t ar1 = (size_t)(row0 + 16 + lr) * DIMS + kj;
    const size_t br0 = (size_t)(col0 + lr) * DIMS + kj;
    const size_t br1 = (size_t)(col0 + 16 + lr) * DIMS + kj;
    f32x4 acc00 = {}, acc01 = {}, acc10 = {}, acc11 = {};
    for (int k0 = 0; k0 < DIMS; k0 += 32) {
        bf16x8 a0h = *(const bf16x8*)(Ahi + ar0 + k0);
        bf16x8 a1h = *(const bf16x8*)(Ahi + ar1 + k0);
        bf16x8 a0l = *(const bf16x8*)(Alo + ar0 + k0);
        bf16x8 a1l = *(const bf16x8*)(Alo + ar1 + k0);
        bf16x8 b0h = *(const bf16x8*)(Bhi + br0 + k0);
        bf16x8 b1h = *(const bf16x8*)(Bhi + br1 + k0);
        bf16x8 b0l = *(const bf16x8*)(Blo + br0 + k0);
        bf16x8 b1l = *(const bf16x8*)(Blo + br1 + k0);
        acc00 = __builtin_amdgcn_mfma_f32_16x16x32_bf16(a0l, b0h, acc00, 0, 0, 0);
        acc00 = __builtin_amdgcn_mfma_f32_16x16x32_bf16(a0h, b0l, acc00, 0, 0, 0);
        acc00 = __builtin_amdgcn_mfma_f32_16x16x32_bf16(a0h, b0h, acc00, 0, 0, 0);
        acc01 = __builtin_amdgcn_mfma_f32_16x16x32_bf16(a0l, b1h, acc01, 0, 0, 0);
        acc01 = __builtin_amdgcn_mfma_f32_16x16x32_bf16(a0h, b1l, acc01, 0, 0, 0);
        acc01 = __builtin_amdgcn_mfma_f32_16x16x32_bf16(a0h, b1h, acc01, 0, 0, 0);
        acc10 = __builtin_amdgcn_mfma_f32_16x16x32_bf16(a1l, b0h, acc10, 0, 0, 0);
        acc10 = __builtin_amdgcn_mfma_f32_16x16x32_bf16(a1h, b0l, acc10, 0, 0, 0);
        acc10 = __builtin_amdgcn_mfma_f32_16x16x32_bf16(a1h, b0h, acc10, 0, 0, 0);
        acc11 = __builtin_amdgcn_mfma_f32_16x16x32_bf16(a1l, b1h, acc11, 0, 0, 0);
        acc11 = __builtin_amdgcn_mfma_f32_16x16x32_bf16(a1h, b1l, acc11, 0, 0, 0);
        acc11 = __builtin_amdgcn_mfma_f32_16x16x32_bf16(a1h, b1h, acc11, 0, 0, 0);
    }
    const int rbase = (lane >> 4) * 4;
    #pragma unroll
    for (int r = 0; r < 4; ++r) {
        Q[(size_t)(row0 + rbase + r) * N_COLS + col0 + lr]           = __expf(-1.0f - acc00[r]);
        Q[(size_t)(row0 + rbase + r) * N_COLS + col0 + 16 + lr]      = __expf(-1.0f - acc01[r]);
        Q[(size_t)(row0 + 16 + rbase + r) * N_COLS + col0 + lr]      = __expf(-1.0f - acc10[r]);
        Q[(size_t)(row0 + 16 + rbase + r) * N_COLS + col0 + 16 + lr] = __expf(-1.0f - acc11[r]);
    }
}

// ------- per-row softmax denom -> rs = log2e/(gamma*denom); also Ew = 2^-rs -------
__global__ __launch_bounds__(256) void rowstat_kernel(const float* __restrict__ Q,
                                                      float* __restrict__ rowscale,
                                                      float* __restrict__ ews) {
    int i = blockIdx.x;
    const float* q = Q + (size_t)i * N_COLS;
    int tid = threadIdx.x;
    float4 x = *(const float4*)(q + tid * 4);
    float4 y = *(const float4*)(q + 1024 + tid * 4);
    float s = x.x + x.y + x.z + x.w + y.x + y.y + y.z + y.w;
    #pragma unroll
    for (int off = 32; off > 0; off >>= 1) s += __shfl_down(s, off);
    __shared__ float red[4];
    if ((tid & 63) == 0) red[tid >> 6] = s;
    __syncthreads();
    if (tid == 0) {
        float denom = 2049.0f + red[0] + red[1] + red[2] + red[3];
        float rs = (LOG2E / GAMMA) / denom;
        rowscale[i] = rs;
        ews[i] = fexp2(-rs);
    }
}

// ---- ELT[col][row] = 2^-rs + 2^(-rs*Q[row][col])  (LINEAR weight), transposed ----
__global__ __launch_bounds__(256) void lgt_kernel(const float* __restrict__ Q,
                                                  const float* __restrict__ rowscale,
                                                  float* __restrict__ ELT) {
    __shared__ float tile[64][65];
    const int row0 = blockIdx.y * 64;
    const int col0 = blockIdx.x * 64;
    const int t = threadIdx.x;
    const int c4 = (t & 15) * 4;
    const int r  = t >> 4;           // 0..15
    #pragma unroll
    for (int rr = 0; rr < 64; rr += 16) {
        int row = row0 + rr + r;
        float rs = rowscale[row];
        float4 v = *(const float4*)(Q + (size_t)row * N_COLS + col0 + c4);
        float e = fexp2(-rs);
        tile[c4 + 0][rr + r] = e + fexp2(-rs * v.x);
        tile[c4 + 1][rr + r] = e + fexp2(-rs * v.y);
        tile[c4 + 2][rr + r] = e + fexp2(-rs * v.z);
        tile[c4 + 3][rr + r] = e + fexp2(-rs * v.w);
    }
    __syncthreads();
    #pragma unroll
    for (int cc = 0; cc < 64; cc += 16) {
        int col = cc + r;
        float4 o;
        o.x = tile[col][c4 + 0];
        o.y = tile[col][c4 + 1];
        o.z = tile[col][c4 + 2];
        o.w = tile[col][c4 + 3];
        *(float4*)(ELT + (size_t)(col0 + col) * M_ROWS + row0 + c4) = o;
    }
}

// Hard materialization point: forces v into a VGPR here (and keeps it there),
// preventing the compiler from sinking the feeding load into the row bodies.
#define KEEP4(v) asm volatile("" : "+v"(v.x), "+v"(v.y), "+v"(v.z), "+v"(v.w))

// ---------------- single-instruction DPP scan stage (round-5-proven) ----------------
#define SST(V, MODS) asm("s_nop 1\n\tv_add_f32_dpp %0, %0, %0 " MODS : "+v"(V))
#define SCAN6                                                            \
    SST(t, "row_shr:1 row_mask:0xf bank_mask:0xf bound_ctrl:0");         \
    SST(t, "row_shr:2 row_mask:0xf bank_mask:0xf bound_ctrl:0");         \
    SST(t, "row_shr:4 row_mask:0xf bank_mask:0xf bound_ctrl:0");         \
    SST(t, "row_shr:8 row_mask:0xf bank_mask:0xf bound_ctrl:0");         \
    SST(t, "row_bcast:15 row_mask:0xa bank_mask:0xf bound_ctrl:0");      \
    SST(t, "row_bcast:31 row_mask:0xc bank_mask:0xf bound_ctrl:0")

// ---------------- linear-space row body (verbatim round 5/10) ----------------
#define DP_ROW(U, ELV, EWV, VCI)                                                 \
    {                                                                            \
        float ci = 0.f;                                                          \
        if (s > 0)                                                               \
            ci = __int_as_float(__builtin_amdgcn_readlane(                       \
                     __float_as_int(VCI), (U)));                                 \
        float t = w * (ELV);                                                     \
        float pre = fmaf(w, (EWV) - (ELV), ci);                                  \
        SCAN6;                                                                   \
        float all = ci + t;                                                      \
        float wn = pre + t;                                                      \
        if (s < DP_BLOCKS - 1) {                                                 \
            if (lane == 63) {                                                    \
                unsigned long long po =                                          \
                    ((unsigned long long)__float_as_uint(all) << 32)             \
                    | (unsigned long long)__float_as_uint(Rm);                   \
                __hip_atomic_store(pub + base + (U), po, __ATOMIC_RELAXED,       \
                                   __HIP_MEMORY_SCOPE_AGENT);                    \
            }                                                                    \
        } else {                                                                 \
            h = fmaf(h, (EWV), all);                                             \
        }                                                                        \
        w = wn;                                                                  \
    }

// Renorm the shared exponent from lane 48's mantissa, every 8 rows.
#define RENORM8                                                                  \
    {                                                                            \
        int e48 = __builtin_amdgcn_readlane(__builtin_amdgcn_frexp_expf(w), 48); \
        float f = __int_as_float((127 - e48) << 23);                             \
        w *= f; h *= f;                                                          \
        Rm += (float)e48;                                                        \
    }

// Band-granular wait (round-10-proven).
#define WAIT_BAND                                                                \
    if (s > 0) {                                                                 \
        for (;;) {                                                               \
            unsigned long long miss = __ballot((lane < BAND) && pk == 0ull);     \
            if (miss == 0ull) break;                                             \
            if (pk == 0ull && lane < BAND)                                       \
                pk = __hip_atomic_load(sub + base + lane, __ATOMIC_RELAXED,      \
                                       __HIP_MEMORY_SCOPE_AGENT);               \
        }                                                                        \
        pkLo = (int)(unsigned)(pk & 0xFFFFFFFFull);                              \
        pkHi = (int)(unsigned)(pk >> 32);                                        \
    }

__global__ __launch_bounds__(64) void dp_kernel(const float* __restrict__ ELT,
                                                const float* __restrict__ Ews,
                                                unsigned long long* __restrict__ carry,
                                                float* __restrict__ out) {
    const int s = ((blockIdx.x & 7) << 2) | (blockIdx.x >> 3);  // XCD-aware stripe id
    const int lane = threadIdx.x;
    const float* lcol = ELT + (size_t)(s * DP_COLS + lane) * M_ROWS;
    unsigned long long* pub = carry + (size_t)s * M_ROWS;
    const unsigned long long* sub = carry + (size_t)(s - 1) * M_ROWS;

    float w = 1.f;                 // virtual row -1: V = 0 for every column
    float Rm = 0.f;                // shared exponent
    float h = 1.f;                 // head accumulator (stripe 31, lane 63)

    float4 lq0 = *(const float4*)(lcol + 0);
    float4 lq1 = *(const float4*)(lcol + 4);
    float4 lq2 = *(const float4*)(lcol + 8);
    float4 lq3 = *(const float4*)(lcol + 12);
    float4 ev0 = *(const float4*)(Ews + 0);
    float4 ev1 = *(const float4*)(Ews + 4);
    float4 ev2 = *(const float4*)(Ews + 8);
    float4 ev3 = *(const float4*)(Ews + 12);
    KEEP4(lq0); KEEP4(lq1); KEEP4(lq2); KEEP4(lq3);
    KEEP4(ev0); KEEP4(ev1); KEEP4(ev2); KEEP4(ev3);

    // speculative carry prefetch for band 0
    unsigned long long pk = 1ull;
    if (s > 0 && lane < BAND)
        pk = __hip_atomic_load(sub + lane, __ATOMIC_RELAXED, __HIP_MEMORY_SCOPE_AGENT);

    for (int base = 0; base < M_ROWS; base += BAND) {
        // prefetch next band's weights; KEEP4 pins them into VGPRs NOW so the
        // 16 rows below are register-only (one exposed load latency per band).
        float4 nl0{}, nl1{}, nl2{}, nl3{}, nv0{}, nv1{}, nv2{}, nv3{};
        if (base + BAND < M_ROWS) {
            nl0 = *(const float4*)(lcol + base + BAND);
            nl1 = *(const float4*)(lcol + base + BAND + 4);
            nl2 = *(const float4*)(lcol + base + BAND + 8);
            nl3 = *(const float4*)(lcol + base + BAND + 12);
            nv0 = *(const float4*)(Ews + base + BAND);
            nv1 = *(const float4*)(Ews + base + BAND + 4);
            nv2 = *(const float4*)(Ews + base + BAND + 8);
            nv3 = *(const float4*)(Ews + base + BAND + 12);
        }
        KEEP4(nl0); KEEP4(nl1); KEEP4(nl2); KEEP4(nl3);
        KEEP4(nv0); KEEP4(nv1); KEEP4(nv2); KEEP4(nv3);

        int pkLo = 0, pkHi = 0;
        WAIT_BAND
        // carry pre-scale for rows 0-7 (producer Rm constant over the half-band)
        float vci01 = 0.f;
        if (s > 0)
            vci01 = __int_as_float(pkHi) * fexp2(
                __int_as_float(__builtin_amdgcn_readlane(pkLo, 0)) - Rm);

        DP_ROW(0,  lq0.x, ev0.x, vci01)
        DP_ROW(1,  lq0.y, ev0.y, vci01)
        DP_ROW(2,  lq0.z, ev0.z, vci01)
        DP_ROW(3,  lq0.w, ev0.w, vci01)
        DP_ROW(4,  lq1.x, ev1.x, vci01)
        DP_ROW(5,  lq1.y, ev1.y, vci01)
        DP_ROW(6,  lq1.z, ev1.z, vci01)
        DP_ROW(7,  lq1.w, ev1.w, vci01)
        RENORM8
        // carry pre-scale for rows 8-15, in the POST-renorm Rm frame
        float vci23 = 0.f;
        if (s > 0)
            vci23 = __int_as_float(pkHi) * fexp2(
                __int_as_float(__builtin_amdgcn_readlane(pkLo, 8)) - Rm);
        // speculative carry load for the NEXT band (~8-row lead)
        unsigned long long nk = 1ull;
        if (s > 0 && lane < BAND && base + BAND < M_ROWS)
            nk = __hip_atomic_load(sub + base + BAND + lane,
                                   __ATOMIC_RELAXED, __HIP_MEMORY_SCOPE_AGENT);

        DP_ROW(8,  lq2.x, ev2.x, vci23)
        DP_ROW(9,  lq2.y, ev2.y, vci23)
        DP_ROW(10, lq2.z, ev2.z, vci23)
        DP_ROW(11, lq2.w, ev2.w, vci23)
        DP_ROW(12, lq3.x, ev3.x, vci23)
        DP_ROW(13, lq3.y, ev3.y, vci23)
        DP_ROW(14, lq3.z, ev3.z, vci23)
        DP_ROW(15, lq3.w, ev3.w, vci23)
        RENORM8
        pk = nk;

        lq0 = nl0; lq1 = nl1; lq2 = nl2; lq3 = nl3;
        ev0 = nv0; ev1 = nv1; ev2 = nv2; ev3 = nv3;
    }
    if (s == DP_BLOCKS - 1 && lane == 63)
        out[0] = -GAMMA * LN2 * (Rm + flog2(h));
}

extern "C" void kernel_launch(void* const* d_in, const int* in_sizes, int n_in,
                              void* d_out, int out_size, void* d_ws, size_t ws_size,
                              hipStream_t stream) {
    (void)in_sizes; (void)n_in; (void)out_size; (void)ws_size;
    const float* a = (const float*)d_in[0];
    const float* b = (const float*)d_in[1];
    float* out = (float*)d_out;
    char* ws = (char*)d_ws;
    float* Q        = (float*)(ws);                                            // 16 MB
    float* ELT      = (float*)(ws + (size_t)16 * 1024 * 1024);                 // 16 MB
    unsigned short* Ahi = (unsigned short*)(ws + (size_t)32 * 1024 * 1024);    // 2 MB
    unsigned short* Alo = (unsigned short*)(ws + (size_t)34 * 1024 * 1024);    // 2 MB
    unsigned short* Bhi = (unsigned short*)(ws + (size_t)36 * 1024 * 1024);    // 2 MB
    unsigned short* Blo = (unsigned short*)(ws + (size_t)38 * 1024 * 1024);    // 2 MB
    float* rowscale = (float*)(ws + (size_t)40 * 1024 * 1024);                 // 8 KB
    int* permA      = (int*)(ws + (size_t)40 * 1024 * 1024 + 8192);            // 8 KB
    int* permB      = (int*)(ws + (size_t)40 * 1024 * 1024 + 16384);           // 8 KB
    float* ews      = (float*)(ws + (size_t)40 * 1024 * 1024 + 24576);         // 8 KB
    unsigned long long* carry = (unsigned long long*)(ws + (size_t)41 * 1024 * 1024); // 512 KB

    hipMemsetAsync(carry, 0, (size_t)DP_BLOCKS * M_ROWS * sizeof(unsigned long long), stream);
    argsort_kernel<<<dim3(8, 2), 256, 0, stream>>>(a, b, permA, permB);
    norm_kernel<<<dim3(2048, 2), 128, 0, stream>>>(a, b, permA, permB, Ahi, Alo, Bhi, Blo);
    gemm_kernel<<<dim3(32, 32), 256, 0, stream>>>(Ahi, Alo, Bhi, Blo, Q);
    rowstat_kernel<<<2048, 256, 0, stream>>>(Q, rowscale, ews);
    lgt_kernel<<<dim3(32, 32), 256, 0, stream>>>(Q, rowscale, ELT);
    dp_kernel<<<DP_BLOCKS, DP_COLS, 0, stream>>>(ELT, ews, carry, out);
}